// Round 10
// baseline (329.105 us; speedup 1.0000x reference)
//
#include <hip/hip_runtime.h>
#include <hip/hip_bf16.h>

#define MASK_ID 3
#define MAX_SEN 128
#define NB 8
#define SEQ 8192
#define EMB 1024
#define DIM 128

typedef __attribute__((ext_vector_type(8))) short short8v;   // 8 bf16
typedef __attribute__((ext_vector_type(4))) float f32x4;     // MFMA accumulator

#define MFMA(a, b, c) __builtin_amdgcn_mfma_f32_16x16x32_bf16(a, b, c, 0, 0, 0)

typedef __attribute__((address_space(1))) const void g_void;
typedef __attribute__((address_space(3))) void l_void;

// fp32 -> bf16 RNE
__device__ __forceinline__ short f2b(float x) {
    union { float f; unsigned u; } v; v.f = x;
    unsigned r = (v.u + 0x7FFFu + ((v.u >> 16) & 1u)) >> 16;
    return (short)r;
}

// hardware packed cvt: [bf16(b)|bf16(a)]
__device__ __forceinline__ unsigned cvtpk(float a, float b) {
    unsigned r;
    asm("v_cvt_pk_bf16_f32 %0, %1, %2" : "=v"(r) : "v"(a), "v"(b));
    return r;
}

__device__ __forceinline__ short8v pack8(float4 a, float4 b) {
    union { short8v s; unsigned u[4]; } r;
    r.u[0] = cvtpk(a.x, a.y);
    r.u[1] = cvtpk(a.z, a.w);
    r.u[2] = cvtpk(b.x, b.y);
    r.u[3] = cvtpk(b.z, b.w);
    return r.s;
}

// ---------------- Kernel 1: per-row scan -> mask positions + nvis ----------------
__global__ __launch_bounds__(1024) void seg_kernel(const int* __restrict__ ids,
                                                   int* __restrict__ pos,
                                                   int* __restrict__ nvis) {
    int b = blockIdx.x;
    int tid = threadIdx.x;
    __shared__ int sc[1024];
    __shared__ int sc2[1024];
    const int PER = SEQ / 1024;  // 8
    int base = b * SEQ + tid * PER;

    int ids_l[PER];
    int cnt = 0;
    #pragma unroll
    for (int j = 0; j < PER; j++) {
        ids_l[j] = ids[base + j];
        cnt += (ids_l[j] == MASK_ID) ? 1 : 0;
    }
    if (tid < MAX_SEN) pos[b * MAX_SEN + tid] = -1;
    sc[tid] = cnt;
    __syncthreads();

    int* src = sc;
    int* dst = sc2;
    for (int off = 1; off < 1024; off <<= 1) {
        int v = src[tid];
        if (tid >= off) v += src[tid - off];
        dst[tid] = v;
        __syncthreads();
        int* t = src; src = dst; dst = t;
    }
    int incl = src[tid];
    int run = incl - cnt;  // exclusive prefix

    #pragma unroll
    for (int j = 0; j < PER; j++) {
        if (ids_l[j] == MASK_ID) {
            run++;
            if (run <= MAX_SEN) pos[b * MAX_SEN + run - 1] = tid * PER + j;
        }
        int nv = run; if (nv > MAX_SEN) nv = MAX_SEN;
        nvis[base + j] = nv;
    }
}

// ---------------- Kernel 2: weights -> bf16 FRAGMENT-TILED layouts (R9-proven) ----------------
__global__ __launch_bounds__(256) void prep_w(const float* __restrict__ Wq,
                                              const float* __restrict__ Wo,
                                              short* __restrict__ WqTt,
                                              short* __restrict__ WoTt) {
    int idx = blockIdx.x * 256 + threadIdx.x;      // 0 .. 131071
    {   // Wq[e][d]: idx = e*128 + d
        int e = idx >> 7, d = idx & 127;
        int c = e >> 6, ks = (e >> 5) & 1, lq = (e >> 3) & 3, j = e & 7;
        int cf = d >> 4, lr = d & 15;
        WqTt[(((c * 2 + ks) * 8 + cf) * 512) + (lq * 16 + lr) * 8 + j] = f2b(Wq[idx]);
    }
    {   // Wo[dd][e]: idx = dd*1024 + e
        int dd = idx >> 10, e = idx & 1023;
        int ef = e >> 4, lr = e & 15;
        int kk = dd >> 5, lq = (dd >> 3) & 3, j = dd & 7;
        WoTt[((ef * 4 + kk) * 512) + (lq * 16 + lr) * 8 + j] = f2b(Wo[idx]);
    }
}

// ---------------- Kernel 3: fused static+kv -> fragment-tiled k/v (R9-proven) ----------------
__global__ __launch_bounds__(128) void statkv_kernel(const float* __restrict__ hidden,
                                                     const float* __restrict__ Wv, const float* __restrict__ bv,
                                                     const float* __restrict__ Wk, const float* __restrict__ bk,
                                                     const float* __restrict__ Wvt, const float* __restrict__ bvt,
                                                     const int* __restrict__ pos,
                                                     short* __restrict__ k_t, short* __restrict__ vT_t) {
    int m = blockIdx.x, b = blockIdx.y;
    int d = threadIdx.x;
    __shared__ float h[EMB];
    __shared__ float srow[DIM];
    int p = pos[b * MAX_SEN + m];   // uniform across block
    float acc = bv[d];
    if (p >= 0) {
        const float* hp = hidden + ((size_t)b * SEQ + p) * EMB;
        for (int e = d; e < EMB; e += 128) h[e] = hp[e];
        __syncthreads();
        float a0 = 0.f, a1 = 0.f, a2 = 0.f, a3 = 0.f;
        for (int e = 0; e < EMB; e += 4) {
            a0 += h[e]     * Wv[e * DIM + d];
            a1 += h[e + 1] * Wv[(e + 1) * DIM + d];
            a2 += h[e + 2] * Wv[(e + 2) * DIM + d];
            a3 += h[e + 3] * Wv[(e + 3) * DIM + d];
        }
        acc += (a0 + a1) + (a2 + a3);
    }
    srow[d] = acc;
    __syncthreads();
    float k0 = 0.f, k1 = 0.f, v0 = 0.f, v1 = 0.f;
    for (int e = 0; e < DIM; e += 2) {
        float s0 = srow[e], s1 = srow[e + 1];
        k0 += s0 * Wk[e * DIM + d];
        k1 += s1 * Wk[(e + 1) * DIM + d];
        v0 += s0 * Wvt[e * DIM + d];
        v1 += s1 * Wvt[(e + 1) * DIM + d];
    }
    {
        int kk = d >> 5, lq = (d >> 3) & 3, j = d & 7;
        int fid = (m >> 4) * 4 + kk;
        k_t[(b << 14) + fid * 512 + (lq * 16 + (m & 15)) * 8 + j] = f2b(bk[d] + k0 + k1);
    }
    {
        int df = d >> 4, kk = m >> 5, lq = (m >> 3) & 3, j = m & 7;
        int fid = df * 4 + kk;
        vT_t[(b << 14) + fid * 512 + (lq * 16 + (d & 15)) * 8 + j] = f2b(bvt[d] + v0 + v1);
    }
}

// ---------------- Kernel 4: q-projection (phase-1 only), 64 rows/block ----------------
// glds width-16 staging (R6-proven source-pre-swizzle) + tiled W frags (R9-proven).
// Output q in FRAGMENT-TILED layout: frag (rf,kk) of 512 shorts, per-block 8192 shorts.
__global__ __launch_bounds__(256, 4) void q_kernel(const float* __restrict__ hidden,
                                                   const short* __restrict__ WqTt,
                                                   const float* __restrict__ bq,
                                                   short* __restrict__ q_t) {
    int blk = blockIdx.x;            // 1024
    int tid = threadIdx.x;
    int lane = tid & 63, w = tid >> 6, lr = lane & 15, lq = lane >> 4;

    __shared__ __align__(16) char SH[32768];
    char* A0 = SH;
    char* A1 = SH + 16384;
    char* qt = SH;                   // aliases A0 (dead after last compute on A1)

    const char* hbytes = (const char*)(hidden + (size_t)blk * 64 * EMB);
    f32x4 zero = {0.f, 0.f, 0.f, 0.f};
    f32x4 acc[4][2];
    #pragma unroll
    for (int rf = 0; rf < 4; rf++) { acc[rf][0] = zero; acc[rf][1] = zero; }

    short8v Wa[4], Wb[4];

#define QSTAGE(C, B) do { \
    int lsub = lane >> 4; \
    int blin = (lane & 15) << 4; \
    _Pragma("unroll") \
    for (int j = 0; j < 4; j++) { \
        int row = w * 16 + j * 4 + lsub; \
        const char* sp = hbytes + (size_t)row * 4096 + (C) * 256 + (blin ^ ((row & 7) << 4)); \
        __builtin_amdgcn_global_load_lds((g_void*)sp, (l_void*)((B) + w * 4096 + j * 1024), 16, 0, 0); \
    } } while (0)

#define QLOADW(C, W) do { \
    const short* wp = WqTt + ((C) * 16 + 2 * w) * 512 + lane * 8; \
    W[0] = *(const short8v*)(wp); \
    W[1] = *(const short8v*)(wp + 512); \
    W[2] = *(const short8v*)(wp + 8 * 512); \
    W[3] = *(const short8v*)(wp + 9 * 512); } while (0)

#define QCOMPUTE(B, W) do { \
    _Pragma("unroll") \
    for (int ks = 0; ks < 2; ks++) { \
        _Pragma("unroll") \
        for (int rf = 0; rf < 4; rf++) { \
            int row = rf * 16 + lr; \
            int x = (row & 7) << 4; \
            int kb = ks * 128 + lq * 32; \
            float4 f0 = *(const float4*)((B) + row * 256 + (kb ^ x)); \
            float4 f1 = *(const float4*)((B) + row * 256 + ((kb + 16) ^ x)); \
            short8v fa = pack8(f0, f1); \
            acc[rf][0] = MFMA(fa, W[ks * 2 + 0], acc[rf][0]); \
            acc[rf][1] = MFMA(fa, W[ks * 2 + 1], acc[rf][1]); \
        } } } while (0)

    QSTAGE(0, A0);
    QLOADW(0, Wa);
    __syncthreads();                 // chunk 0 resident
    for (int c = 0; c < 16; c += 2) {
        if (c + 1 < 16) { QSTAGE(c + 1, A1); QLOADW(c + 1, Wb); }
        QCOMPUTE(A0, Wa);
        __syncthreads();             // chunk c+1 resident; A0 free
        if (c + 2 < 16) { QSTAGE(c + 2, A0); QLOADW(c + 2, Wa); }
        QCOMPUTE(A1, Wb);
        __syncthreads();             // chunk c+2 resident; A1 free
    }

    // epilogue: acc -> (bias+scale) -> bf16 -> LDS frag layout -> coalesced store
    {
        const float scale = 0.08838834764831845f;  // 128^-0.5
        float bq0 = bq[w * 32 + lr], bq1 = bq[w * 32 + 16 + lr];
        #pragma unroll
        for (int rf = 0; rf < 4; rf++)
            #pragma unroll
            for (int r = 0; r < 4; r++) {
                // cfi = 0: col = w*32 + lr; cfi = 1: col = w*32 + 16 + lr
                short v0 = f2b((acc[rf][0][r] + bq0) * scale);
                short v1 = f2b((acc[rf][1][r] + bq1) * scale);
                int lp0 = ((lr >> 3) * 16) + lq * 4 + r;            // cfi=0: lane' = (0*2+(lr>>3))*16 + ...
                int lp1 = ((2 + (lr >> 3)) * 16) + lq * 4 + r;      // cfi=1
                int j = (lr & 7) * 2;
                *(short*)(qt + (rf * 4 + w) * 1024 + lp0 * 16 + j) = v0;
                *(short*)(qt + (rf * 4 + w) * 1024 + lp1 * 16 + j) = v1;
            }
    }
    __syncthreads();
    #pragma unroll
    for (int f2 = 0; f2 < 4; f2++) {
        short8v vfrag = *(short8v*)(qt + (w * 4 + f2) * 1024 + lane * 16);
        *(short8v*)(q_t + (size_t)blk * 8192 + (w * 4 + f2) * 512 + lane * 8) = vfrag;
    }
}

// ---------------- Kernel 5: logits -> softmax -> PV -> out-proj, 64 tokens/block ----------------
// q read as tiled fragments straight from global (no q LDS). 32KB LDS total.
__global__ __launch_bounds__(256, 4) void atto_kernel(const short* __restrict__ q_t,
                                                      const short* __restrict__ k_t,
                                                      const short* __restrict__ vT_t,
                                                      const short* __restrict__ WoTt,
                                                      const float* __restrict__ bo,
                                                      const int* __restrict__ nvis,
                                                      float* __restrict__ out) {
    // XCD swizzle: XCD x owns batch x (K/V L2-resident)
    int wg = (blockIdx.x & 7) * 128 + (blockIdx.x >> 3);
    int b  = wg >> 7;
    int s0 = (wg & 127) * 64;
    int tid = threadIdx.x;
    int lane = tid & 63;
    int w  = tid >> 6;
    int lr = lane & 15;
    int lq = lane >> 4;

    // LDS 32KB: lg = 64 rows x 512B swz [0,32K); after B3: pP [0,16K), od [16K,32K)
    __shared__ __align__(16) char SH[32768];
    char* pPc = SH;
    char* odc = SH + 16384;

    const size_t hrow = (size_t)b * SEQ + s0;
    f32x4 zero = {0.f, 0.f, 0.f, 0.f};

    // ---- phase 2: logits = q @ K^T (all operands tiled-global) ----
    {
        f32x4 l[4][2];
        #pragma unroll
        for (int rf = 0; rf < 4; rf++) { l[rf][0] = zero; l[rf][1] = zero; }
        const short* qb    = q_t + (size_t)wg * 8192 + lane * 8;
        const short* kbase = k_t + (b << 14) + (2 * w) * 4 * 512 + lane * 8;
        #pragma unroll
        for (int kk = 0; kk < 4; kk++) {
            const short8v fb0 = *(const short8v*)(kbase + kk * 512);
            const short8v fb1 = *(const short8v*)(kbase + (4 + kk) * 512);
            #pragma unroll
            for (int rf = 0; rf < 4; rf++) {
                short8v fa = *(const short8v*)(qb + (rf * 4 + kk) * 512);
                l[rf][0] = MFMA(fa, fb0, l[rf][0]);
                l[rf][1] = MFMA(fa, fb1, l[rf][1]);
            }
        }
        #pragma unroll
        for (int rf = 0; rf < 4; rf++)
            #pragma unroll
            for (int r = 0; r < 4; r++) {
                int row = rf * 16 + lq * 4 + r;
                int x = (row & 7) << 4;
                *(float*)(SH + row * 512 + (((w * 32 + lr) * 4) ^ x))      = l[rf][0][r];
                *(float*)(SH + row * 512 + (((w * 32 + 16 + lr) * 4) ^ x)) = l[rf][1][r];
            }
    }
    __syncthreads();   // B2: logits visible

    // ---- phase 3: masked softmax (4 threads/token, 32 m each) ----
    {
        int t = tid >> 2, sub = tid & 3;
        int nv = nvis[b * SEQ + s0 + t];
        int x = (t & 7) << 4;
        float pv[32];
        #pragma unroll
        for (int u = 0; u < 8; u++) {
            float4 v = *(const float4*)(SH + t * 512 + ((sub * 128 + u * 16) ^ x));
            pv[u * 4]     = v.x; pv[u * 4 + 1] = v.y;
            pv[u * 4 + 2] = v.z; pv[u * 4 + 3] = v.w;
        }
        int base_m = sub * 32;
        float mx = -3.0e38f;
        #pragma unroll
        for (int i = 0; i < 32; i++)
            mx = (base_m + i < nv) ? fmaxf(mx, pv[i]) : mx;
        mx = fmaxf(mx, __shfl_xor(mx, 1));
        mx = fmaxf(mx, __shfl_xor(mx, 2));
        float sum = 0.f;
        #pragma unroll
        for (int i = 0; i < 32; i++) {
            float e = (base_m + i < nv) ? __expf(pv[i] - mx) : 0.f;
            pv[i] = e;
            sum += e;
        }
        sum += __shfl_xor(sum, 1);
        sum += __shfl_xor(sum, 2);
        float inv = (nv > 0) ? 1.0f / sum : 0.f;

        __syncthreads();   // B3: all lg reads done; region becomes pP/od

        #pragma unroll
        for (int u = 0; u < 4; u++) {
            union { short8v s; unsigned uu[4]; } p;
            #pragma unroll
            for (int i = 0; i < 4; i++)
                p.uu[i] = cvtpk(pv[u * 8 + 2 * i] * inv, pv[u * 8 + 2 * i + 1] * inv);
            *(short8v*)(pPc + t * 256 + ((sub * 64 + u * 16) ^ x)) = p.s;
        }
    }
    __syncthreads();   // B4: P visible

    // ---- phase 4: od = P @ V ----
    {
        f32x4 o[4][2];
        #pragma unroll
        for (int rf = 0; rf < 4; rf++) { o[rf][0] = zero; o[rf][1] = zero; }
        const short* vbase = vT_t + (b << 14) + (2 * w) * 4 * 512 + lane * 8;
        #pragma unroll
        for (int kk = 0; kk < 4; kk++) {
            const short8v fb0 = *(const short8v*)(vbase + kk * 512);
            const short8v fb1 = *(const short8v*)(vbase + (4 + kk) * 512);
            #pragma unroll
            for (int rf = 0; rf < 4; rf++) {
                int row = rf * 16 + lr;
                int x = (row & 7) << 4;
                short8v fa = *(short8v*)(pPc + row * 256 + ((kk * 64 + lq * 16) ^ x));
                o[rf][0] = MFMA(fa, fb0, o[rf][0]);
                o[rf][1] = MFMA(fa, fb1, o[rf][1]);
            }
        }
        int d0 = w * 32 + lr;
        #pragma unroll
        for (int rf = 0; rf < 4; rf++)
            #pragma unroll
            for (int r = 0; r < 4; r++) {
                int row = rf * 16 + lq * 4 + r;
                int x = (row & 7) << 4;
                *(short*)(odc + row * 256 + ((d0 * 2) ^ x))        = f2b(o[rf][0][r]);
                *(short*)(odc + row * 256 + (((d0 + 16) * 2) ^ x)) = f2b(o[rf][1][r]);
            }
    }
    __syncthreads();   // B5: od visible

    // ---- phase 5: out = od @ Wo + bo (wave w -> col quarter) ----
    {
        short8v af[4][4];
        #pragma unroll
        for (int rf = 0; rf < 4; rf++)
            #pragma unroll
            for (int kk = 0; kk < 4; kk++) {
                int row = rf * 16 + lr;
                int x = (row & 7) << 4;
                af[rf][kk] = *(short8v*)(odc + row * 256 + ((kk * 64 + lq * 16) ^ x));
            }
        #pragma unroll
        for (int grp = 0; grp < 4; grp++) {
            int colbase = w * 256 + grp * 64;
            f32x4 ac[4][4];
            #pragma unroll
            for (int rf = 0; rf < 4; rf++)
                #pragma unroll
                for (int cf = 0; cf < 4; cf++) ac[rf][cf] = zero;
            #pragma unroll
            for (int kk = 0; kk < 4; kk++) {
                #pragma unroll
                for (int cf = 0; cf < 4; cf++) {
                    const short8v bb = *(const short8v*)(WoTt
                        + ((w * 16 + grp * 4 + cf) * 4 + kk) * 512 + lane * 8);
                    #pragma unroll
                    for (int rf = 0; rf < 4; rf++)
                        ac[rf][cf] = MFMA(af[rf][kk], bb, ac[rf][cf]);
                }
            }
            #pragma unroll
            for (int cf = 0; cf < 4; cf++) {
                int col = colbase + cf * 16 + lr;
                float bov = bo[col];
                #pragma unroll
                for (int rf = 0; rf < 4; rf++)
                    #pragma unroll
                    for (int r = 0; r < 4; r++)
                        out[(hrow + rf * 16 + lq * 4 + r) * EMB + col] = ac[rf][cf][r] + bov;
            }
        }
    }
}

extern "C" void kernel_launch(void* const* d_in, const int* in_sizes, int n_in,
                              void* d_out, int out_size, void* d_ws, size_t ws_size,
                              hipStream_t stream) {
    const int*   ids    = (const int*)d_in[0];
    const float* hidden = (const float*)d_in[1];
    const float* Wv     = (const float*)d_in[2];
    const float* bv     = (const float*)d_in[3];
    const float* Wq     = (const float*)d_in[4];
    const float* bq     = (const float*)d_in[5];
    const float* Wk     = (const float*)d_in[6];
    const float* bk     = (const float*)d_in[7];
    const float* Wvt    = (const float*)d_in[8];
    const float* bvt    = (const float*)d_in[9];
    const float* Wo     = (const float*)d_in[10];
    const float* bo     = (const float*)d_in[11];

    char* ws = (char*)d_ws;
    int*   pos   = (int*)ws;                                   // 4 KB
    int*   nvis  = (int*)(ws + (4 << 10));                     // 256 KB
    short* k_t   = (short*)(ws + (260 << 10));                 // 256 KB tiled
    short* vT_t  = (short*)(ws + (516 << 10));                 // 256 KB tiled
    short* WqTt  = (short*)(ws + (772 << 10));                 // 256 KB tiled
    short* WoTt  = (short*)(ws + (1028 << 10));                // 256 KB tiled
    short* q_t   = (short*)(ws + (1284 << 10));                // 16 MB tiled q

    seg_kernel<<<NB, 1024, 0, stream>>>(ids, pos, nvis);
    prep_w<<<512, 256, 0, stream>>>(Wq, Wo, WqTt, WoTt);
    dim3 g2(MAX_SEN, NB);
    statkv_kernel<<<g2, 128, 0, stream>>>(hidden, Wv, bv, Wk, bk, Wvt, bvt, pos, k_t, vT_t);
    q_kernel<<<NB * (SEQ / 64), 256, 0, stream>>>(hidden, WqTt, bq, q_t);
    atto_kernel<<<NB * (SEQ / 64), 256, 0, stream>>>(q_t, k_t, vT_t, WoTt, bo, nvis,
                                                     (float*)d_out);
}

// Round 11
// 293.714 us; speedup vs baseline: 1.1205x; 1.1205x over previous
//
#include <hip/hip_runtime.h>
#include <hip/hip_bf16.h>

#define MASK_ID 3
#define MAX_SEN 128
#define NB 8
#define SEQ 8192
#define EMB 1024
#define DIM 128

typedef __attribute__((ext_vector_type(8))) short short8v;   // 8 bf16
typedef __attribute__((ext_vector_type(4))) float f32x4;     // MFMA accumulator

#define MFMA(a, b, c) __builtin_amdgcn_mfma_f32_16x16x32_bf16(a, b, c, 0, 0, 0)

// fp32 -> bf16 RNE
__device__ __forceinline__ short f2b(float x) {
    union { float f; unsigned u; } v; v.f = x;
    unsigned r = (v.u + 0x7FFFu + ((v.u >> 16) & 1u)) >> 16;
    return (short)r;
}

// hardware packed cvt: [bf16(b)|bf16(a)]
__device__ __forceinline__ unsigned cvtpk(float a, float b) {
    unsigned r;
    asm("v_cvt_pk_bf16_f32 %0, %1, %2" : "=v"(r) : "v"(a), "v"(b));
    return r;
}

__device__ __forceinline__ short8v pack8(float4 a, float4 b) {
    union { short8v s; unsigned u[4]; } r;
    r.u[0] = cvtpk(a.x, a.y);
    r.u[1] = cvtpk(a.z, a.w);
    r.u[2] = cvtpk(b.x, b.y);
    r.u[3] = cvtpk(b.z, b.w);
    return r.s;
}

// ---------------- Kernel 1: per-row scan -> mask positions + nvis ----------------
__global__ __launch_bounds__(1024) void seg_kernel(const int* __restrict__ ids,
                                                   int* __restrict__ pos,
                                                   int* __restrict__ nvis) {
    int b = blockIdx.x;
    int tid = threadIdx.x;
    __shared__ int sc[1024];
    __shared__ int sc2[1024];
    const int PER = SEQ / 1024;  // 8
    int base = b * SEQ + tid * PER;

    int ids_l[PER];
    int cnt = 0;
    #pragma unroll
    for (int j = 0; j < PER; j++) {
        ids_l[j] = ids[base + j];
        cnt += (ids_l[j] == MASK_ID) ? 1 : 0;
    }
    if (tid < MAX_SEN) pos[b * MAX_SEN + tid] = -1;
    sc[tid] = cnt;
    __syncthreads();

    int* src = sc;
    int* dst = sc2;
    for (int off = 1; off < 1024; off <<= 1) {
        int v = src[tid];
        if (tid >= off) v += src[tid - off];
        dst[tid] = v;
        __syncthreads();
        int* t = src; src = dst; dst = t;
    }
    int incl = src[tid];
    int run = incl - cnt;  // exclusive prefix

    #pragma unroll
    for (int j = 0; j < PER; j++) {
        if (ids_l[j] == MASK_ID) {
            run++;
            if (run <= MAX_SEN) pos[b * MAX_SEN + run - 1] = tid * PER + j;
        }
        int nv = run; if (nv > MAX_SEN) nv = MAX_SEN;
        nvis[base + j] = nv;
    }
}

// ---------------- Kernel 2: weights -> bf16 FRAGMENT-TILED layouts (R9-proven) ----------------
__global__ __launch_bounds__(256) void prep_w(const float* __restrict__ Wq,
                                              const float* __restrict__ Wo,
                                              short* __restrict__ WqTt,
                                              short* __restrict__ WoTt) {
    int idx = blockIdx.x * 256 + threadIdx.x;      // 0 .. 131071
    {   // Wq[e][d]: idx = e*128 + d
        int e = idx >> 7, d = idx & 127;
        int c = e >> 6, ks = (e >> 5) & 1, lq = (e >> 3) & 3, j = e & 7;
        int cf = d >> 4, lr = d & 15;
        WqTt[(((c * 2 + ks) * 8 + cf) * 512) + (lq * 16 + lr) * 8 + j] = f2b(Wq[idx]);
    }
    {   // Wo[dd][e]: idx = dd*1024 + e
        int dd = idx >> 10, e = idx & 1023;
        int ef = e >> 4, lr = e & 15;
        int kk = dd >> 5, lq = (dd >> 3) & 3, j = dd & 7;
        WoTt[((ef * 4 + kk) * 512) + (lq * 16 + lr) * 8 + j] = f2b(Wo[idx]);
    }
}

// ---------------- Kernel 3: fused static+kv -> fragment-tiled k/v (R9-proven) ----------------
__global__ __launch_bounds__(128) void statkv_kernel(const float* __restrict__ hidden,
                                                     const float* __restrict__ Wv, const float* __restrict__ bv,
                                                     const float* __restrict__ Wk, const float* __restrict__ bk,
                                                     const float* __restrict__ Wvt, const float* __restrict__ bvt,
                                                     const int* __restrict__ pos,
                                                     short* __restrict__ k_t, short* __restrict__ vT_t) {
    int m = blockIdx.x, b = blockIdx.y;
    int d = threadIdx.x;
    __shared__ float h[EMB];
    __shared__ float srow[DIM];
    int p = pos[b * MAX_SEN + m];   // uniform across block
    float acc = bv[d];
    if (p >= 0) {
        const float* hp = hidden + ((size_t)b * SEQ + p) * EMB;
        for (int e = d; e < EMB; e += 128) h[e] = hp[e];
        __syncthreads();
        float a0 = 0.f, a1 = 0.f, a2 = 0.f, a3 = 0.f;
        for (int e = 0; e < EMB; e += 4) {
            a0 += h[e]     * Wv[e * DIM + d];
            a1 += h[e + 1] * Wv[(e + 1) * DIM + d];
            a2 += h[e + 2] * Wv[(e + 2) * DIM + d];
            a3 += h[e + 3] * Wv[(e + 3) * DIM + d];
        }
        acc += (a0 + a1) + (a2 + a3);
    }
    srow[d] = acc;
    __syncthreads();
    float k0 = 0.f, k1 = 0.f, v0 = 0.f, v1 = 0.f;
    for (int e = 0; e < DIM; e += 2) {
        float s0 = srow[e], s1 = srow[e + 1];
        k0 += s0 * Wk[e * DIM + d];
        k1 += s1 * Wk[(e + 1) * DIM + d];
        v0 += s0 * Wvt[e * DIM + d];
        v1 += s1 * Wvt[(e + 1) * DIM + d];
    }
    {
        int kk = d >> 5, lq = (d >> 3) & 3, j = d & 7;
        int fid = (m >> 4) * 4 + kk;
        k_t[(b << 14) + fid * 512 + (lq * 16 + (m & 15)) * 8 + j] = f2b(bk[d] + k0 + k1);
    }
    {
        int df = d >> 4, kk = m >> 5, lq = (m >> 3) & 3, j = m & 7;
        int fid = df * 4 + kk;
        vT_t[(b << 14) + fid * 512 + (lq * 16 + (d & 15)) * 8 + j] = f2b(bvt[d] + v0 + v1);
    }
}

// ---------------- Kernel 4: fused MFMA attention, 64 tokens/block, 32KB LDS ----------------
// Swapped QK^T: S[m][t] = mfma(K_frag, q_frag) -> lane holds 32 logits of ONE
// token -> in-register masked softmax (2x shfl_xor), no lg buffer, 2 fewer
// barriers, LDS 48->32KB -> 4 blocks/CU.
__global__ __launch_bounds__(256, 4) void attn_kernel(
    const float* __restrict__ hidden,
    const short* __restrict__ WqTt, const float* __restrict__ bq,
    const short* __restrict__ k_t, const short* __restrict__ vT_t,
    const short* __restrict__ WoTt, const float* __restrict__ bo,
    const int* __restrict__ nvis,
    float* __restrict__ out) {
    // XCD swizzle: XCD x owns batch x (K/V L2-resident)
    int wg = (blockIdx.x & 7) * 128 + (blockIdx.x >> 3);
    int b  = wg >> 7;
    int s0 = (wg & 127) * 64;
    int tid = threadIdx.x;
    int lane = tid & 63;
    int w  = tid >> 6;             // wave 0..3
    int lr = lane & 15;
    int lq = lane >> 4;            // quarter 0..3

    // LDS 32KB: ph1: Ab [0,8K), qP [8K,24K).
    // after B2: pP [0,16K) (Ab + qP rows 0-31 dead); after B3: od [16K,32K).
    __shared__ __align__(16) char SH[32768];
    char* Ab  = SH;
    char* qPc = SH + 8192;
    char* pPc = SH;
    char* odc = SH + 16384;

    const size_t hrow = (size_t)b * SEQ + s0;
    const char* hbytes = (const char*)(hidden + hrow * EMB);
    (void)hbytes;
    const float* hbase = hidden + hrow * EMB;
    (void)hbase;
    f32x4 zero = {0.f, 0.f, 0.f, 0.f};

    // ================= phase 1: q = (H @ Wq + bq) * scale =================
    f32x4 acc[4][2];
    #pragma unroll
    for (int rf = 0; rf < 4; rf++) { acc[rf][0] = zero; acc[rf][1] = zero; }

    int G0 = tid * 2, row0 = G0 >> 3, kq0 = G0 & 7;
    int G1 = G0 + 1,  row1 = G1 >> 3, kq1 = G1 & 7;
    const float* ha0 = hidden + (hrow + row0) * EMB + kq0 * 8;
    const float* ha1 = hidden + (hrow + row1) * EMB + kq1 * 8;
    int dst0 = (row0 * 128 + kq0 * 16) ^ ((row0 & 7) << 4);
    int dst1 = (row1 * 128 + kq1 * 16) ^ ((row1 & 7) << 4);

    float4 pa[4];
    short8v Wa[4], Wb[4];

#define LOADA(C) do { \
    pa[0] = *(const float4*)(ha0 + (C) * 64); \
    pa[1] = *(const float4*)(ha0 + (C) * 64 + 4); \
    pa[2] = *(const float4*)(ha1 + (C) * 64); \
    pa[3] = *(const float4*)(ha1 + (C) * 64 + 4); } while (0)

#define LOADW(C, W) do { \
    const short* wp = WqTt + ((C) * 16 + 2 * w) * 512 + lane * 8; \
    W[0] = *(const short8v*)(wp); \
    W[1] = *(const short8v*)(wp + 512); \
    W[2] = *(const short8v*)(wp + 8 * 512); \
    W[3] = *(const short8v*)(wp + 9 * 512); } while (0)

#define STORE_A() do { \
    *(short8v*)(Ab + dst0) = pack8(pa[0], pa[1]); \
    *(short8v*)(Ab + dst1) = pack8(pa[2], pa[3]); } while (0)

#define COMPUTE(W) do { \
    _Pragma("unroll") \
    for (int ks = 0; ks < 2; ks++) { \
        _Pragma("unroll") \
        for (int rf = 0; rf < 4; rf++) { \
            int row = rf * 16 + lr; \
            short8v fa = *(short8v*)(Ab + ((row * 128 + ks * 64 + lq * 16) ^ ((row & 7) << 4))); \
            acc[rf][0] = MFMA(fa, W[ks * 2 + 0], acc[rf][0]); \
            acc[rf][1] = MFMA(fa, W[ks * 2 + 1], acc[rf][1]); \
        } } } while (0)

    // prologue
    LOADA(0);
    LOADW(0, Wa);

    for (int c = 0; c < 16; c += 2) {
        __syncthreads();          // readers of previous chunk done
        STORE_A();
        LOADA(c + 1);
        LOADW(c + 1, Wb);
        __syncthreads();          // chunk c visible
        COMPUTE(Wa);

        __syncthreads();
        STORE_A();
        if (c + 2 < 16) {
            LOADA(c + 2);
            LOADW(c + 2, Wa);
        }
        __syncthreads();
        COMPUTE(Wb);
    }
    {
        const float scale = 0.08838834764831845f;  // 128^-0.5
        int d0 = w * 32 + lr;
        float bq0 = bq[d0], bq1 = bq[d0 + 16];
        #pragma unroll
        for (int rf = 0; rf < 4; rf++)
            #pragma unroll
            for (int r = 0; r < 4; r++) {
                int row = rf * 16 + lq * 4 + r;
                int x = (row & 7) << 4;
                *(short*)(qPc + row * 256 + ((d0 * 2) ^ x))        = f2b((acc[rf][0][r] + bq0) * scale);
                *(short*)(qPc + row * 256 + (((d0 + 16) * 2) ^ x)) = f2b((acc[rf][1][r] + bq1) * scale);
            }
    }
    __syncthreads();   // B1: q visible

    // ========== phase 2 (swapped): S[m][t] = K @ q^T ; in-register softmax ==========
    // Wave w owns tokens t = w*16 + lr. Lane holds S for m = mf*16 + lq*4 + r.
    {
        f32x4 S[8];
        #pragma unroll
        for (int mf = 0; mf < 8; mf++) S[mf] = zero;
        const short* kbase = k_t + (b << 14) + lane * 8;
        int tl = w * 16 + lr;
        int xq = (tl & 7) << 4;
        #pragma unroll
        for (int kk = 0; kk < 4; kk++) {
            short8v fb = *(short8v*)(qPc + tl * 256 + ((kk * 64 + lq * 16) ^ xq));
            #pragma unroll
            for (int mf = 0; mf < 8; mf++) {
                const short8v fa = *(const short8v*)(kbase + (mf * 4 + kk) * 512);
                S[mf] = MFMA(fa, fb, S[mf]);
            }
        }
        __syncthreads();   // B2: all qP reads done; region becomes pP

        int nv = nvis[b * SEQ + s0 + tl];
        float mx = -3.0e38f;
        #pragma unroll
        for (int mf = 0; mf < 8; mf++)
            #pragma unroll
            for (int r = 0; r < 4; r++) {
                int m = mf * 16 + lq * 4 + r;
                mx = (m < nv) ? fmaxf(mx, S[mf][r]) : mx;
            }
        mx = fmaxf(mx, __shfl_xor(mx, 16));
        mx = fmaxf(mx, __shfl_xor(mx, 32));
        float sum = 0.f;
        #pragma unroll
        for (int mf = 0; mf < 8; mf++)
            #pragma unroll
            for (int r = 0; r < 4; r++) {
                int m = mf * 16 + lq * 4 + r;
                float e = (m < nv) ? __expf(S[mf][r] - mx) : 0.f;
                S[mf][r] = e;
                sum += e;
            }
        sum += __shfl_xor(sum, 16);
        sum += __shfl_xor(sum, 32);
        float inv = (nv > 0) ? 1.0f / sum : 0.f;

        #pragma unroll
        for (int mf = 0; mf < 8; mf++) {
            unsigned lo = cvtpk(S[mf][0] * inv, S[mf][1] * inv);
            unsigned hi = cvtpk(S[mf][2] * inv, S[mf][3] * inv);
            char* wp = pPc + tl * 256 + ((mf * 32 + lq * 8) ^ xq);
            *(unsigned long long*)wp = ((unsigned long long)hi << 32) | (unsigned long long)lo;
        }
    }
    __syncthreads();   // B3: P visible

    // ================= phase 4: od = P @ V =================
    {
        f32x4 o[4][2];
        #pragma unroll
        for (int rf = 0; rf < 4; rf++) { o[rf][0] = zero; o[rf][1] = zero; }
        const short* vbase = vT_t + (b << 14) + (2 * w) * 4 * 512 + lane * 8;
        #pragma unroll
        for (int kk = 0; kk < 4; kk++) {
            const short8v fb0 = *(const short8v*)(vbase + kk * 512);
            const short8v fb1 = *(const short8v*)(vbase + (4 + kk) * 512);
            #pragma unroll
            for (int rf = 0; rf < 4; rf++) {
                int row = rf * 16 + lr;
                int x = (row & 7) << 4;
                short8v fa = *(short8v*)(pPc + row * 256 + ((kk * 64 + lq * 16) ^ x));
                o[rf][0] = MFMA(fa, fb0, o[rf][0]);
                o[rf][1] = MFMA(fa, fb1, o[rf][1]);
            }
        }
        int d0 = w * 32 + lr;
        #pragma unroll
        for (int rf = 0; rf < 4; rf++)
            #pragma unroll
            for (int r = 0; r < 4; r++) {
                int row = rf * 16 + lq * 4 + r;
                int x = (row & 7) << 4;
                *(short*)(odc + row * 256 + ((d0 * 2) ^ x))        = f2b(o[rf][0][r]);
                *(short*)(odc + row * 256 + (((d0 + 16) * 2) ^ x)) = f2b(o[rf][1][r]);
            }
    }
    __syncthreads();   // B4: od visible

    // ================= phase 5: out = od @ Wo + bo (wave w -> col quarter) =================
    {
        short8v af[4][4];
        #pragma unroll
        for (int rf = 0; rf < 4; rf++)
            #pragma unroll
            for (int kk = 0; kk < 4; kk++) {
                int row = rf * 16 + lr;
                int x = (row & 7) << 4;
                af[rf][kk] = *(short8v*)(odc + row * 256 + ((kk * 64 + lq * 16) ^ x));
            }
        #pragma unroll
        for (int grp = 0; grp < 4; grp++) {
            int colbase = w * 256 + grp * 64;
            f32x4 ac[4][4];
            #pragma unroll
            for (int rf = 0; rf < 4; rf++)
                #pragma unroll
                for (int cf = 0; cf < 4; cf++) ac[rf][cf] = zero;
            #pragma unroll
            for (int kk = 0; kk < 4; kk++) {
                #pragma unroll
                for (int cf = 0; cf < 4; cf++) {
                    const short8v bb = *(const short8v*)(WoTt
                        + ((w * 16 + grp * 4 + cf) * 4 + kk) * 512 + lane * 8);
                    #pragma unroll
                    for (int rf = 0; rf < 4; rf++)
                        ac[rf][cf] = MFMA(af[rf][kk], bb, ac[rf][cf]);
                }
            }
            #pragma unroll
            for (int cf = 0; cf < 4; cf++) {
                int col = colbase + cf * 16 + lr;
                float bov = bo[col];
                #pragma unroll
                for (int rf = 0; rf < 4; rf++)
                    #pragma unroll
                    for (int r = 0; r < 4; r++)
                        out[(hrow + rf * 16 + lq * 4 + r) * EMB + col] = ac[rf][cf][r] + bov;
            }
        }
    }
}

extern "C" void kernel_launch(void* const* d_in, const int* in_sizes, int n_in,
                              void* d_out, int out_size, void* d_ws, size_t ws_size,
                              hipStream_t stream) {
    const int*   ids    = (const int*)d_in[0];
    const float* hidden = (const float*)d_in[1];
    const float* Wv     = (const float*)d_in[2];
    const float* bv     = (const float*)d_in[3];
    const float* Wq     = (const float*)d_in[4];
    const float* bq     = (const float*)d_in[5];
    const float* Wk     = (const float*)d_in[6];
    const float* bk     = (const float*)d_in[7];
    const float* Wvt    = (const float*)d_in[8];
    const float* bvt    = (const float*)d_in[9];
    const float* Wo     = (const float*)d_in[10];
    const float* bo     = (const float*)d_in[11];

    char* ws = (char*)d_ws;
    int*   pos   = (int*)ws;                                   // 4 KB
    int*   nvis  = (int*)(ws + (4 << 10));                     // 256 KB
    short* k_t   = (short*)(ws + (260 << 10));                 // 256 KB tiled
    short* vT_t  = (short*)(ws + (516 << 10));                 // 256 KB tiled
    short* WqTt  = (short*)(ws + (772 << 10));                 // 256 KB tiled
    short* WoTt  = (short*)(ws + (1028 << 10));                // 256 KB tiled

    seg_kernel<<<NB, 1024, 0, stream>>>(ids, pos, nvis);
    prep_w<<<512, 256, 0, stream>>>(Wq, Wo, WqTt, WoTt);
    dim3 g2(MAX_SEN, NB);
    statkv_kernel<<<g2, 128, 0, stream>>>(hidden, Wv, bv, Wk, bk, Wvt, bvt, pos, k_t, vT_t);
    attn_kernel<<<NB * (SEQ / 64), 256, 0, stream>>>(hidden, WqTt, bq, k_t, vT_t, WoTt, bo,
                                                     nvis, (float*)d_out);
}

// Round 12
// 228.734 us; speedup vs baseline: 1.4388x; 1.2841x over previous
//
#include <hip/hip_runtime.h>
#include <hip/hip_bf16.h>

#define MASK_ID 3
#define MAX_SEN 128
#define NB 8
#define SEQ 8192
#define EMB 1024
#define DIM 128

typedef __attribute__((ext_vector_type(8))) short short8v;   // 8 bf16
typedef __attribute__((ext_vector_type(4))) float f32x4;     // MFMA accumulator

#define MFMA(a, b, c) __builtin_amdgcn_mfma_f32_16x16x32_bf16(a, b, c, 0, 0, 0)

// fp32 -> bf16 RNE
__device__ __forceinline__ short f2b(float x) {
    union { float f; unsigned u; } v; v.f = x;
    unsigned r = (v.u + 0x7FFFu + ((v.u >> 16) & 1u)) >> 16;
    return (short)r;
}

// hardware packed cvt: [bf16(b)|bf16(a)]
__device__ __forceinline__ unsigned cvtpk(float a, float b) {
    unsigned r;
    asm("v_cvt_pk_bf16_f32 %0, %1, %2" : "=v"(r) : "v"(a), "v"(b));
    return r;
}

__device__ __forceinline__ short8v pack8(float4 a, float4 b) {
    union { short8v s; unsigned u[4]; } r;
    r.u[0] = cvtpk(a.x, a.y);
    r.u[1] = cvtpk(a.z, a.w);
    r.u[2] = cvtpk(b.x, b.y);
    r.u[3] = cvtpk(b.z, b.w);
    return r.s;
}

// ---------------- Kernel 1: per-row scan -> mask positions + nvis ----------------
__global__ __launch_bounds__(1024) void seg_kernel(const int* __restrict__ ids,
                                                   int* __restrict__ pos,
                                                   int* __restrict__ nvis) {
    int b = blockIdx.x;
    int tid = threadIdx.x;
    __shared__ int sc[1024];
    __shared__ int sc2[1024];
    const int PER = SEQ / 1024;  // 8
    int base = b * SEQ + tid * PER;

    int ids_l[PER];
    int cnt = 0;
    #pragma unroll
    for (int j = 0; j < PER; j++) {
        ids_l[j] = ids[base + j];
        cnt += (ids_l[j] == MASK_ID) ? 1 : 0;
    }
    if (tid < MAX_SEN) pos[b * MAX_SEN + tid] = -1;
    sc[tid] = cnt;
    __syncthreads();

    int* src = sc;
    int* dst = sc2;
    for (int off = 1; off < 1024; off <<= 1) {
        int v = src[tid];
        if (tid >= off) v += src[tid - off];
        dst[tid] = v;
        __syncthreads();
        int* t = src; src = dst; dst = t;
    }
    int incl = src[tid];
    int run = incl - cnt;  // exclusive prefix

    #pragma unroll
    for (int j = 0; j < PER; j++) {
        if (ids_l[j] == MASK_ID) {
            run++;
            if (run <= MAX_SEN) pos[b * MAX_SEN + run - 1] = tid * PER + j;
        }
        int nv = run; if (nv > MAX_SEN) nv = MAX_SEN;
        nvis[base + j] = nv;
    }
}

// ---------------- Kernel 2: weights -> bf16 FRAGMENT-TILED layouts (R9-proven) ----------------
__global__ __launch_bounds__(256) void prep_w(const float* __restrict__ Wq,
                                              const float* __restrict__ Wo,
                                              short* __restrict__ WqTt,
                                              short* __restrict__ WoTt) {
    int idx = blockIdx.x * 256 + threadIdx.x;      // 0 .. 131071
    {   // Wq[e][d]: idx = e*128 + d
        int e = idx >> 7, d = idx & 127;
        int c = e >> 6, ks = (e >> 5) & 1, lq = (e >> 3) & 3, j = e & 7;
        int cf = d >> 4, lr = d & 15;
        WqTt[(((c * 2 + ks) * 8 + cf) * 512) + (lq * 16 + lr) * 8 + j] = f2b(Wq[idx]);
    }
    {   // Wo[dd][e]: idx = dd*1024 + e
        int dd = idx >> 10, e = idx & 1023;
        int ef = e >> 4, lr = e & 15;
        int kk = dd >> 5, lq = (dd >> 3) & 3, j = dd & 7;
        WoTt[((ef * 4 + kk) * 512) + (lq * 16 + lr) * 8 + j] = f2b(Wo[idx]);
    }
}

// ---------------- Kernel 3: fused static+kv -> fragment-tiled k/v (R9-proven) ----------------
__global__ __launch_bounds__(128) void statkv_kernel(const float* __restrict__ hidden,
                                                     const float* __restrict__ Wv, const float* __restrict__ bv,
                                                     const float* __restrict__ Wk, const float* __restrict__ bk,
                                                     const float* __restrict__ Wvt, const float* __restrict__ bvt,
                                                     const int* __restrict__ pos,
                                                     short* __restrict__ k_t, short* __restrict__ vT_t) {
    int m = blockIdx.x, b = blockIdx.y;
    int d = threadIdx.x;
    __shared__ float h[EMB];
    __shared__ float srow[DIM];
    int p = pos[b * MAX_SEN + m];   // uniform across block
    float acc = bv[d];
    if (p >= 0) {
        const float* hp = hidden + ((size_t)b * SEQ + p) * EMB;
        for (int e = d; e < EMB; e += 128) h[e] = hp[e];
        __syncthreads();
        float a0 = 0.f, a1 = 0.f, a2 = 0.f, a3 = 0.f;
        for (int e = 0; e < EMB; e += 4) {
            a0 += h[e]     * Wv[e * DIM + d];
            a1 += h[e + 1] * Wv[(e + 1) * DIM + d];
            a2 += h[e + 2] * Wv[(e + 2) * DIM + d];
            a3 += h[e + 3] * Wv[(e + 3) * DIM + d];
        }
        acc += (a0 + a1) + (a2 + a3);
    }
    srow[d] = acc;
    __syncthreads();
    float k0 = 0.f, k1 = 0.f, v0 = 0.f, v1 = 0.f;
    for (int e = 0; e < DIM; e += 2) {
        float s0 = srow[e], s1 = srow[e + 1];
        k0 += s0 * Wk[e * DIM + d];
        k1 += s1 * Wk[(e + 1) * DIM + d];
        v0 += s0 * Wvt[e * DIM + d];
        v1 += s1 * Wvt[(e + 1) * DIM + d];
    }
    {
        int kk = d >> 5, lq = (d >> 3) & 3, j = d & 7;
        int fid = (m >> 4) * 4 + kk;
        k_t[(b << 14) + fid * 512 + (lq * 16 + (m & 15)) * 8 + j] = f2b(bk[d] + k0 + k1);
    }
    {
        int df = d >> 4, kk = m >> 5, lq = (m >> 3) & 3, j = m & 7;
        int fid = df * 4 + kk;
        vT_t[(b << 14) + fid * 512 + (lq * 16 + (d & 15)) * 8 + j] = f2b(bvt[d] + v0 + v1);
    }
}

// ---------------- Kernel 4: fused MFMA attention, 64 tokens/block ----------------
// R9 + phase-1 counted-wait pipeline: raw s_barrier pairs (NO vmcnt drain),
// 3-deep named A-prefetch (pa0/1/2), lgkmcnt(0)+sched_barrier for ds_write
// visibility (rule #18). Phases 2-5 identical to R9.
__global__ __launch_bounds__(256, 3) void attn_kernel(
    const float* __restrict__ hidden,
    const short* __restrict__ WqTt, const float* __restrict__ bq,
    const short* __restrict__ k_t, const short* __restrict__ vT_t,
    const short* __restrict__ WoTt, const float* __restrict__ bo,
    const int* __restrict__ nvis,
    float* __restrict__ out) {
    // XCD swizzle: XCD x owns batch x (K/V L2-resident)
    int wg = (blockIdx.x & 7) * 128 + (blockIdx.x >> 3);
    int b  = wg >> 7;
    int s0 = (wg & 127) * 64;
    int tid = threadIdx.x;
    int lane = tid & 63;
    int w  = tid >> 6;             // wave 0..3
    int lr = lane & 15;
    int lq = lane >> 4;            // quarter 0..3

    // LDS 48KB: ph1: Ab bf16 chunk [0,8K), qP [32K,48K).
    // ph2-3: lg 64x512B swz [0,32K). ph3+: pP [0,16K), od [16K,32K).
    __shared__ __align__(16) char SH[49152];
    char* Ab  = SH;
    char* pPc = SH;
    char* odc = SH + 16384;
    char* qPc = SH + 32768;

    const size_t hrow = (size_t)b * SEQ + s0;
    f32x4 zero = {0.f, 0.f, 0.f, 0.f};

    // ================= phase 1: q = (H @ Wq + bq) * scale =================
    f32x4 acc[4][2];
    #pragma unroll
    for (int rf = 0; rf < 4; rf++) { acc[rf][0] = zero; acc[rf][1] = zero; }

    int G0 = tid * 2, row0 = G0 >> 3, kq0 = G0 & 7;
    int G1 = G0 + 1,  row1 = G1 >> 3, kq1 = G1 & 7;
    const float* ha0 = hidden + (hrow + row0) * EMB + kq0 * 8;
    const float* ha1 = hidden + (hrow + row1) * EMB + kq1 * 8;
    int dst0 = (row0 * 128 + kq0 * 16) ^ ((row0 & 7) << 4);
    int dst1 = (row1 * 128 + kq1 * 16) ^ ((row1 & 7) << 4);

    float4 pa0[4], pa1[4], pa2[4];
    short8v Wa[4], Wb[4];

#define LOADA(C, PA) do { \
    PA[0] = *(const float4*)(ha0 + (C) * 64); \
    PA[1] = *(const float4*)(ha0 + (C) * 64 + 4); \
    PA[2] = *(const float4*)(ha1 + (C) * 64); \
    PA[3] = *(const float4*)(ha1 + (C) * 64 + 4); } while (0)

#define LOADW(C, W) do { \
    const short* wp = WqTt + ((C) * 16 + 2 * w) * 512 + lane * 8; \
    W[0] = *(const short8v*)(wp); \
    W[1] = *(const short8v*)(wp + 512); \
    W[2] = *(const short8v*)(wp + 8 * 512); \
    W[3] = *(const short8v*)(wp + 9 * 512); } while (0)

#define STORE_A(PA) do { \
    *(short8v*)(Ab + dst0) = pack8(PA[0], PA[1]); \
    *(short8v*)(Ab + dst1) = pack8(PA[2], PA[3]); } while (0)

#define COMPUTE(W) do { \
    _Pragma("unroll") \
    for (int ks = 0; ks < 2; ks++) { \
        _Pragma("unroll") \
        for (int rf = 0; rf < 4; rf++) { \
            int row = rf * 16 + lr; \
            short8v fa = *(short8v*)(Ab + ((row * 128 + ks * 64 + lq * 16) ^ ((row & 7) << 4))); \
            acc[rf][0] = MFMA(fa, W[ks * 2 + 0], acc[rf][0]); \
            acc[rf][1] = MFMA(fa, W[ks * 2 + 1], acc[rf][1]); \
        } } } while (0)

// Pipeline iteration: vmcnt is NEVER force-drained; only lgkmcnt(0) before the
// post-barrier (ds_write visibility). Raw s_barrier (no implicit drains).
#define ITER(c, PA, WW, DO_A, DO_W) do { \
    __builtin_amdgcn_s_barrier();                 /* readers of chunk c-1 done */ \
    STORE_A(PA);                                  /* counted wait on PA only  */ \
    if (DO_A) LOADA((c) + 3, PA); \
    asm volatile("s_waitcnt lgkmcnt(0)" ::: "memory"); \
    __builtin_amdgcn_sched_barrier(0); \
    __builtin_amdgcn_s_barrier();                 /* chunk c visible          */ \
    COMPUTE(WW); \
    if (DO_W) LOADW((c) + 2, WW);                 /* refill consumed slot     */ \
    } while (0)

    // prologue: W first (consumed earliest), then 3 A-chunks
    LOADW(0, Wa);
    LOADW(1, Wb);
    LOADA(0, pa0);
    LOADA(1, pa1);
    LOADA(2, pa2);

    ITER(0,  pa0, Wa, 1, 1);
    ITER(1,  pa1, Wb, 1, 1);
    ITER(2,  pa2, Wa, 1, 1);
    ITER(3,  pa0, Wb, 1, 1);
    ITER(4,  pa1, Wa, 1, 1);
    ITER(5,  pa2, Wb, 1, 1);
    ITER(6,  pa0, Wa, 1, 1);
    ITER(7,  pa1, Wb, 1, 1);
    ITER(8,  pa2, Wa, 1, 1);
    ITER(9,  pa0, Wb, 1, 1);
    ITER(10, pa1, Wa, 1, 1);
    ITER(11, pa2, Wb, 1, 1);
    ITER(12, pa0, Wa, 1, 1);
    ITER(13, pa1, Wb, 0, 1);
    ITER(14, pa2, Wa, 0, 0);
    ITER(15, pa0, Wb, 0, 0);

    {
        const float scale = 0.08838834764831845f;  // 128^-0.5
        int d0 = w * 32 + lr;
        float bq0 = bq[d0], bq1 = bq[d0 + 16];
        #pragma unroll
        for (int rf = 0; rf < 4; rf++)
            #pragma unroll
            for (int r = 0; r < 4; r++) {
                int row = rf * 16 + lq * 4 + r;
                int x = (row & 7) << 4;
                *(short*)(qPc + row * 256 + ((d0 * 2) ^ x))        = f2b((acc[rf][0][r] + bq0) * scale);
                *(short*)(qPc + row * 256 + (((d0 + 16) * 2) ^ x)) = f2b((acc[rf][1][r] + bq1) * scale);
            }
    }
    __syncthreads();   // B1: q visible; Ab dead -> lg region live

    // ================= phase 2: logits = q @ K^T =================
    {
        f32x4 l[4][2];
        #pragma unroll
        for (int rf = 0; rf < 4; rf++) { l[rf][0] = zero; l[rf][1] = zero; }
        const short* kbase = k_t + (b << 14) + (2 * w) * 4 * 512 + lane * 8;
        #pragma unroll
        for (int kk = 0; kk < 4; kk++) {
            const short8v fb0 = *(const short8v*)(kbase + kk * 512);
            const short8v fb1 = *(const short8v*)(kbase + (4 + kk) * 512);
            #pragma unroll
            for (int rf = 0; rf < 4; rf++) {
                int row = rf * 16 + lr;
                int x = (row & 7) << 4;
                short8v fa = *(short8v*)(qPc + row * 256 + ((kk * 64 + lq * 16) ^ x));
                l[rf][0] = MFMA(fa, fb0, l[rf][0]);
                l[rf][1] = MFMA(fa, fb1, l[rf][1]);
            }
        }
        #pragma unroll
        for (int rf = 0; rf < 4; rf++)
            #pragma unroll
            for (int r = 0; r < 4; r++) {
                int row = rf * 16 + lq * 4 + r;
                int x = (row & 7) << 4;
                *(float*)(SH + row * 512 + (((w * 32 + lr) * 4) ^ x))      = l[rf][0][r];
                *(float*)(SH + row * 512 + (((w * 32 + 16 + lr) * 4) ^ x)) = l[rf][1][r];
            }
    }
    __syncthreads();   // B2: logits visible

    // ================= phase 3: masked softmax (4 threads/token, 32 m each) =================
    {
        int t = tid >> 2, sub = tid & 3;
        int nv = nvis[b * SEQ + s0 + t];
        int x = (t & 7) << 4;
        float pv[32];
        #pragma unroll
        for (int u = 0; u < 8; u++) {
            float4 v = *(const float4*)(SH + t * 512 + ((sub * 128 + u * 16) ^ x));
            pv[u * 4]     = v.x; pv[u * 4 + 1] = v.y;
            pv[u * 4 + 2] = v.z; pv[u * 4 + 3] = v.w;
        }
        int base_m = sub * 32;
        float mx = -3.0e38f;
        #pragma unroll
        for (int i = 0; i < 32; i++)
            mx = (base_m + i < nv) ? fmaxf(mx, pv[i]) : mx;
        mx = fmaxf(mx, __shfl_xor(mx, 1));
        mx = fmaxf(mx, __shfl_xor(mx, 2));
        float sum = 0.f;
        #pragma unroll
        for (int i = 0; i < 32; i++) {
            float e = (base_m + i < nv) ? __expf(pv[i] - mx) : 0.f;
            pv[i] = e;
            sum += e;
        }
        sum += __shfl_xor(sum, 1);
        sum += __shfl_xor(sum, 2);
        float inv = (nv > 0) ? 1.0f / sum : 0.f;

        __syncthreads();   // B3: all lg reads done; region becomes pP/od

        #pragma unroll
        for (int u = 0; u < 4; u++) {
            union { short8v s; unsigned uu[4]; } p;
            #pragma unroll
            for (int i = 0; i < 4; i++)
                p.uu[i] = cvtpk(pv[u * 8 + 2 * i] * inv, pv[u * 8 + 2 * i + 1] * inv);
            *(short8v*)(pPc + t * 256 + ((sub * 64 + u * 16) ^ x)) = p.s;
        }
    }
    __syncthreads();   // B4: P visible

    // ================= phase 4: od = P @ V =================
    {
        f32x4 o[4][2];
        #pragma unroll
        for (int rf = 0; rf < 4; rf++) { o[rf][0] = zero; o[rf][1] = zero; }
        const short* vbase = vT_t + (b << 14) + (2 * w) * 4 * 512 + lane * 8;
        #pragma unroll
        for (int kk = 0; kk < 4; kk++) {
            const short8v fb0 = *(const short8v*)(vbase + kk * 512);
            const short8v fb1 = *(const short8v*)(vbase + (4 + kk) * 512);
            #pragma unroll
            for (int rf = 0; rf < 4; rf++) {
                int row = rf * 16 + lr;
                int x = (row & 7) << 4;
                short8v fa = *(short8v*)(pPc + row * 256 + ((kk * 64 + lq * 16) ^ x));
                o[rf][0] = MFMA(fa, fb0, o[rf][0]);
                o[rf][1] = MFMA(fa, fb1, o[rf][1]);
            }
        }
        int d0 = w * 32 + lr;
        #pragma unroll
        for (int rf = 0; rf < 4; rf++)
            #pragma unroll
            for (int r = 0; r < 4; r++) {
                int row = rf * 16 + lq * 4 + r;
                int x = (row & 7) << 4;
                *(short*)(odc + row * 256 + ((d0 * 2) ^ x))        = f2b(o[rf][0][r]);
                *(short*)(odc + row * 256 + (((d0 + 16) * 2) ^ x)) = f2b(o[rf][1][r]);
            }
    }
    __syncthreads();   // B5: od visible

    // ================= phase 5: out = od @ Wo + bo (wave w -> col quarter) =================
    {
        short8v af[4][4];
        #pragma unroll
        for (int rf = 0; rf < 4; rf++)
            #pragma unroll
            for (int kk = 0; kk < 4; kk++) {
                int row = rf * 16 + lr;
                int x = (row & 7) << 4;
                af[rf][kk] = *(short8v*)(odc + row * 256 + ((kk * 64 + lq * 16) ^ x));
            }
        #pragma unroll
        for (int grp = 0; grp < 4; grp++) {
            int colbase = w * 256 + grp * 64;
            f32x4 ac[4][4];
            #pragma unroll
            for (int rf = 0; rf < 4; rf++)
                #pragma unroll
                for (int cf = 0; cf < 4; cf++) ac[rf][cf] = zero;
            #pragma unroll
            for (int kk = 0; kk < 4; kk++) {
                #pragma unroll
                for (int cf = 0; cf < 4; cf++) {
                    const short8v bb = *(const short8v*)(WoTt
                        + ((w * 16 + grp * 4 + cf) * 4 + kk) * 512 + lane * 8);
                    #pragma unroll
                    for (int rf = 0; rf < 4; rf++)
                        ac[rf][cf] = MFMA(af[rf][kk], bb, ac[rf][cf]);
                }
            }
            #pragma unroll
            for (int cf = 0; cf < 4; cf++) {
                int col = colbase + cf * 16 + lr;
                float bov = bo[col];
                #pragma unroll
                for (int rf = 0; rf < 4; rf++)
                    #pragma unroll
                    for (int r = 0; r < 4; r++)
                        out[(hrow + rf * 16 + lq * 4 + r) * EMB + col] = ac[rf][cf][r] + bov;
            }
        }
    }
}

extern "C" void kernel_launch(void* const* d_in, const int* in_sizes, int n_in,
                              void* d_out, int out_size, void* d_ws, size_t ws_size,
                              hipStream_t stream) {
    const int*   ids    = (const int*)d_in[0];
    const float* hidden = (const float*)d_in[1];
    const float* Wv     = (const float*)d_in[2];
    const float* bv     = (const float*)d_in[3];
    const float* Wq     = (const float*)d_in[4];
    const float* bq     = (const float*)d_in[5];
    const float* Wk     = (const float*)d_in[6];
    const float* bk     = (const float*)d_in[7];
    const float* Wvt    = (const float*)d_in[8];
    const float* bvt    = (const float*)d_in[9];
    const float* Wo     = (const float*)d_in[10];
    const float* bo     = (const float*)d_in[11];

    char* ws = (char*)d_ws;
    int*   pos   = (int*)ws;                                   // 4 KB
    int*   nvis  = (int*)(ws + (4 << 10));                     // 256 KB
    short* k_t   = (short*)(ws + (260 << 10));                 // 256 KB tiled
    short* vT_t  = (short*)(ws + (516 << 10));                 // 256 KB tiled
    short* WqTt  = (short*)(ws + (772 << 10));                 // 256 KB tiled
    short* WoTt  = (short*)(ws + (1028 << 10));                // 256 KB tiled

    seg_kernel<<<NB, 1024, 0, stream>>>(ids, pos, nvis);
    prep_w<<<512, 256, 0, stream>>>(Wq, Wo, WqTt, WoTt);
    dim3 g2(MAX_SEN, NB);
    statkv_kernel<<<g2, 128, 0, stream>>>(hidden, Wv, bv, Wk, bk, Wvt, bvt, pos, k_t, vT_t);
    attn_kernel<<<NB * (SEQ / 64), 256, 0, stream>>>(hidden, WqTt, bq, k_t, vT_t, WoTt, bo,
                                                     nvis, (float*)d_out);
}